// Round 4
// baseline (716.195 us; speedup 1.0000x reference)
//
#include <hip/hip_runtime.h>
#include <hip/hip_bf16.h>
#include <math.h>

// Problem constants (fixed by reference setup_inputs)
#define N_TOK 8192   // B*S = 4*2048
#define DIM   1024   // D
#define HID   4096   // H
#define NEXP  8      // E
#define CAP   2048   // ceil(1.0 * 2 * 8192 / 8)

typedef short bf16x8 __attribute__((ext_vector_type(8)));
typedef float f32x4  __attribute__((ext_vector_type(4)));

__device__ __forceinline__ unsigned short f2bf(float f) {
    union { float f; unsigned u; } v; v.f = f;
    unsigned r = v.u;
    unsigned lsb = (r >> 16) & 1u;
    r += 0x7fffu + lsb;          // round-to-nearest-even on bf16 boundary
    return (unsigned short)(r >> 16);
}

// Branch-free GELU: erf via Abramowitz-Stegun 7.1.26 (|err|<=1.5e-7).
__device__ __forceinline__ float gelu_f(float v) {
    float az = fabsf(v);
    float z  = az * 0.70710678118654752f;
    float t  = __builtin_amdgcn_rcpf(fmaf(0.3275911f, z, 1.0f));
    float p  = fmaf(fmaf(fmaf(fmaf(1.061405429f, t, -1.453152027f),
                               t, 1.421413741f), t, -0.284496736f), t, 0.254829592f) * t;
    float ez = __expf(-z * z);
    float q5 = 0.5f * p * ez;
    float phi = (v >= 0.f) ? (1.f - q5) : q5;
    return v * phi;
}

// ---------------------------------------------------------------------------
// init: invalidate slot->token map
// ---------------------------------------------------------------------------
__global__ __launch_bounds__(256) void init_kernel(int* __restrict__ slot_token) {
    int gid = blockIdx.x * 256 + threadIdx.x;
    slot_token[gid] = -1;
}

// ---------------------------------------------------------------------------
// transpose + fp32->bf16 convert:  in fp32 [E][R][C]  ->  out bf16 [E][C][R]
// ---------------------------------------------------------------------------
__global__ __launch_bounds__(256) void transpose_convert_kernel(
        const float* __restrict__ in, unsigned short* __restrict__ outp,
        int R, int C) {
    int e  = blockIdx.z;
    int c0 = blockIdx.x * 64, r0 = blockIdx.y * 64;
    __shared__ float tile[64][65];
    const float* ip = in + (size_t)e * R * C;
    unsigned short* op = outp + (size_t)e * R * C;
    int t = threadIdx.x;
    int rr = t >> 4, cc = (t & 15) * 4;
    #pragma unroll
    for (int p = 0; p < 4; ++p) {
        f32x4 v = *(const f32x4*)(ip + (size_t)(r0 + p * 16 + rr) * C + c0 + cc);
        tile[p * 16 + rr][cc + 0] = v[0];
        tile[p * 16 + rr][cc + 1] = v[1];
        tile[p * 16 + rr][cc + 2] = v[2];
        tile[p * 16 + rr][cc + 3] = v[3];
    }
    __syncthreads();
    int ct = t >> 4, rq = (t & 15) * 4;
    #pragma unroll
    for (int p = 0; p < 4; ++p) {
        int c = p * 16 + ct;
        ushort4 o;
        o.x = f2bf(tile[rq + 0][c]);
        o.y = f2bf(tile[rq + 1][c]);
        o.z = f2bf(tile[rq + 2][c]);
        o.w = f2bf(tile[rq + 3][c]);
        *(ushort4*)(op + (size_t)(c0 + c) * R + r0 + rq) = o;
    }
}

// ---------------------------------------------------------------------------
// gate: one wave per token. fp32 logits, softmax, top-2, normalized gates.
// ---------------------------------------------------------------------------
__global__ __launch_bounds__(256) void gate_kernel(
        const float* __restrict__ x, const float* __restrict__ wg,
        int* __restrict__ tok_e, float* __restrict__ tok_g) {
    int wave = threadIdx.x >> 6, lane = threadIdx.x & 63;
    int n = blockIdx.x * 4 + wave;
    const float* xr = x + (size_t)n * DIM;
    float acc[8];
    #pragma unroll
    for (int e = 0; e < 8; ++e) acc[e] = 0.f;
    for (int j = 0; j < DIM / 64; ++j) {
        int d = lane + 64 * j;
        float xv = xr[d];
        const f32x4* wr = (const f32x4*)(wg + (size_t)d * 8);
        f32x4 w0 = wr[0], w1 = wr[1];
        acc[0] += xv * w0[0]; acc[1] += xv * w0[1];
        acc[2] += xv * w0[2]; acc[3] += xv * w0[3];
        acc[4] += xv * w1[0]; acc[5] += xv * w1[1];
        acc[6] += xv * w1[2]; acc[7] += xv * w1[3];
    }
    #pragma unroll
    for (int off = 32; off > 0; off >>= 1) {
        #pragma unroll
        for (int e = 0; e < 8; ++e) acc[e] += __shfl_down(acc[e], off);
    }
    if (lane == 0) {
        float mx = acc[0];
        #pragma unroll
        for (int e = 1; e < 8; ++e) mx = fmaxf(mx, acc[e]);
        float p[8], s = 0.f;
        #pragma unroll
        for (int e = 0; e < 8; ++e) { p[e] = expf(acc[e] - mx); s += p[e]; }
        int i0 = 0;
        #pragma unroll
        for (int e = 1; e < 8; ++e) if (acc[e] > acc[i0]) i0 = e;
        int i1 = (i0 == 0) ? 1 : 0;
        #pragma unroll
        for (int e = 0; e < 8; ++e) if (e != i0 && acc[e] > acc[i1]) i1 = e;
        float g0 = p[i0] / s, g1 = p[i1] / s;
        float gs = fmaxf(g0 + g1, 1e-9f);
        tok_e[n * 2 + 0] = i0;  tok_e[n * 2 + 1] = i1;
        tok_g[n * 2 + 0] = g0 / gs;  tok_g[n * 2 + 1] = g1 / gs;
    }
}

// ---------------------------------------------------------------------------
// route: GShard capacity positions. 1 block, 8 waves; wave w owns expert w.
// ---------------------------------------------------------------------------
__global__ __launch_bounds__(512) void route_kernel(
        const int* __restrict__ tok_e,
        int* __restrict__ slot_token, int* __restrict__ tok_slot) {
    __shared__ int te[N_TOK];      // 32 KB
    int w = threadIdx.x >> 6;      // expert id
    int lane = threadIdx.x & 63;
    unsigned long long below = (lane == 63) ? 0x7fffffffffffffffull
                                            : ((1ull << lane) - 1ull);
    int cnt = 0;
    for (int kk = 0; kk < 2; ++kk) {
        __syncthreads();
        for (int i = threadIdx.x; i < N_TOK; i += 512) te[i] = tok_e[i * 2 + kk];
        __syncthreads();
        #pragma unroll 4
        for (int base = 0; base < N_TOK; base += 64) {
            int n = base + lane;
            bool mine = (te[n] == w);
            unsigned long long m = __ballot(mine);
            if (mine) {
                int pos = cnt + __popcll(m & below);
                bool ok = pos < CAP;
                tok_slot[n * 2 + kk] = ok ? (w * CAP + pos) : -1;
                if (ok) slot_token[w * CAP + pos] = n;
            }
            cnt += __popcll(m);
        }
    }
}

// ---------------------------------------------------------------------------
// dispatch: gather token rows into bf16 disp[E*CAP][DIM]; zero empty slots
// ---------------------------------------------------------------------------
__global__ __launch_bounds__(256) void dispatch_kernel(
        const float* __restrict__ x, const int* __restrict__ slot_token,
        unsigned short* __restrict__ disp) {
    int s = blockIdx.x;
    int tok = slot_token[s];
    int t = threadIdx.x;
    unsigned short* dp = disp + (size_t)s * DIM + t * 4;
    uint2 o;
    if (tok < 0) { o.x = 0u; o.y = 0u; }
    else {
        const f32x4 v = *(const f32x4*)(x + (size_t)tok * DIM + t * 4);
        o.x = (unsigned)f2bf(v[0]) | ((unsigned)f2bf(v[1]) << 16);
        o.y = (unsigned)f2bf(v[2]) | ((unsigned)f2bf(v[3]) << 16);
    }
    *(uint2*)dp = o;
}

// ---------------------------------------------------------------------------
// 256x256 GEMM core — true m201 8-phase schedule (T2+T3+T4+T5):
//   BM=BN=256, BK=64, 512 threads = 8 waves (2M x 4N), per-wave C = 128x64.
//   Per K-tile: 4 phases = (k-half, n-pair) quadrants, each
//     {ds_read subtile | stage 1 half-tile -> barrier -> lgkmcnt(0) ->
//      setprio(1) + 16 MFMA + setprio(0) -> barrier}.
//   Staging leads 1.5-2 K-tiles; counted vmcnt(6) once per K-tile (phase 3),
//   vmcnt(0) only at T==NT-2. Region-overwrite ledger verified:
//     ph0 stage: B-khi(T+1) -> nxt buf (B-khi(T-1) closed at T-1 ph3)
//     ph1 stage: A-klo(T+2) -> cur buf (A-klo(T) closed at ph0)
//     ph2 stage: B-klo(T+2) -> cur buf (B-klo(T) closed at ph1)
//     ph3 stage: A-khi(T+2) -> cur buf (A-khi(T) closed at ph2)
//   Stripe-transposed LDS (zero bank conflicts, verified r2/r3) unchanged.
// ---------------------------------------------------------------------------
template<int KD>
__device__ __forceinline__ void mainloop256(
        const unsigned short* __restrict__ Ag, const unsigned short* __restrict__ Bg,
        unsigned short* lds, f32x4 (&acc)[8][4]) {
    const int t = threadIdx.x;
    const int w = t >> 6, l = t & 63;
    const int wm = w >> 2, wn = w & 3;

    const int slot0 = w * 64 + l;
    const int slot1 = 512 + w * 64 + l;
    const int r0 = (slot0 >> 6) * 16 + (slot0 & 15), c0 = (slot0 >> 4) & 3;
    const int r1 = (slot1 >> 6) * 16 + (slot1 & 15), c1 = (slot1 >> 4) & 3;
    const size_t ofs0 = (size_t)r0 * KD + c0 * 8;
    const size_t ofs1 = (size_t)r1 * KD + c1 * 8;
    const int dst0 = (w * 64) * 8;
    const int dst1 = (512 + w * 64) * 8;

    // one half-tile = 2 global_load_lds per wave = 2 vmcnt ticks
    auto stage = [&](const unsigned short* G, int ldsbase, int kh, int kt) {
        __builtin_amdgcn_global_load_lds(
            (const __attribute__((address_space(1))) void*)(G + ofs0 + kt + kh * 32),
            (__attribute__((address_space(3))) void*)(lds + ldsbase + kh * 8192 + dst0), 16, 0, 0);
        __builtin_amdgcn_global_load_lds(
            (const __attribute__((address_space(1))) void*)(G + ofs1 + kt + kh * 32),
            (__attribute__((address_space(3))) void*)(lds + ldsbase + kh * 8192 + dst1), 16, 0, 0);
    };
    auto ldA = [&](int abase, int ks, int m) {
        return *(const bf16x8*)(lds + abase + ks * 8192 + (wm * 8 + m) * 512 + l * 8);
    };
    auto ldB = [&](int bbase, int ks, int n) {
        return *(const bf16x8*)(lds + bbase + ks * 8192 + (wn * 4 + n) * 512 + l * 8);
    };

#define MFMA16(nlo)                                                                        \
    __builtin_amdgcn_s_setprio(1);                                                        \
    _Pragma("unroll")                                                                      \
    for (int m = 0; m < 8; ++m) {                                                          \
        acc[m][nlo]     = __builtin_amdgcn_mfma_f32_16x16x32_bf16(af[m], bf[nlo],     acc[m][nlo],     0, 0, 0); \
        acc[m][nlo + 1] = __builtin_amdgcn_mfma_f32_16x16x32_bf16(af[m], bf[nlo + 1], acc[m][nlo + 1], 0, 0, 0); \
    }                                                                                      \
    __builtin_amdgcn_s_setprio(0);

#define OPEN_SYNC                                                                          \
    __builtin_amdgcn_sched_barrier(0);                                                     \
    __builtin_amdgcn_s_barrier();                                                          \
    asm volatile("s_waitcnt lgkmcnt(0)" ::: "memory");                                     \
    __builtin_amdgcn_sched_barrier(0);

    constexpr int NT = KD / 64;
    bf16x8 af[8], bf[4];

    // prologue: tile0 complete + 3 half-tiles of tile1 (A-klo, B-klo, A-khi)
    stage(Ag, 0, 0, 0);       stage(Bg, 16384, 0, 0);
    stage(Ag, 0, 1, 0);       stage(Bg, 16384, 1, 0);
    if (NT > 1) {
        stage(Ag, 32768, 0, 64);  stage(Bg, 49152, 0, 64);
        stage(Ag, 32768, 1, 64);
        asm volatile("s_waitcnt vmcnt(6)" ::: "memory");
    } else {
        asm volatile("s_waitcnt vmcnt(0)" ::: "memory");
    }
    __builtin_amdgcn_s_barrier();

#pragma unroll 1
    for (int T = 0; T < NT; ++T) {
        const int cur = T & 1;
        const int abase = cur * 32768, bbase = abase + 16384;
        const int nA = (cur ^ 1) * 32768, nB = nA + 16384;

        // -------- phase 0: ks=0, n in {0,1} --------
        #pragma unroll
        for (int m = 0; m < 8; ++m) af[m] = ldA(abase, 0, m);
        bf[0] = ldB(bbase, 0, 0);  bf[1] = ldB(bbase, 0, 1);
        if (T + 1 < NT) stage(Bg, nB, 1, (T + 1) * 64);        // B-khi(T+1)
        OPEN_SYNC
        MFMA16(0)
        __builtin_amdgcn_s_barrier();

        // -------- phase 1: ks=0, n in {2,3} --------
        bf[2] = ldB(bbase, 0, 2);  bf[3] = ldB(bbase, 0, 3);
        if (T + 2 < NT) stage(Ag, abase, 0, (T + 2) * 64);     // A-klo(T+2)
        OPEN_SYNC
        MFMA16(2)
        __builtin_amdgcn_s_barrier();

        // -------- phase 2: ks=1, n in {0,1} --------
        #pragma unroll
        for (int m = 0; m < 8; ++m) af[m] = ldA(abase, 1, m);
        bf[0] = ldB(bbase, 1, 0);  bf[1] = ldB(bbase, 1, 1);
        if (T + 2 < NT) stage(Bg, bbase, 0, (T + 2) * 64);     // B-klo(T+2)
        OPEN_SYNC
        MFMA16(0)
        __builtin_amdgcn_s_barrier();

        // -------- phase 3: ks=1, n in {2,3} --------
        bf[2] = ldB(bbase, 1, 2);  bf[3] = ldB(bbase, 1, 3);
        if (T + 2 < NT) stage(Ag, abase, 1, (T + 2) * 64);     // A-khi(T+2)
        OPEN_SYNC
        MFMA16(2)
        if (T < NT - 2)       { asm volatile("s_waitcnt vmcnt(6)" ::: "memory"); }
        else if (T == NT - 2) { asm volatile("s_waitcnt vmcnt(0)" ::: "memory"); }
        if (T < NT - 1) __builtin_amdgcn_s_barrier();
    }
#undef MFMA16
#undef OPEN_SYNC
}

// GEMM1: h[e] = gelu(disp[e] @ w1[e] + b1[e]),  M=CAP, N=HID, K=DIM
__global__ __launch_bounds__(512, 2) void gemm1_kernel(
        const unsigned short* __restrict__ disp, const unsigned short* __restrict__ w1t,
        const float* __restrict__ b1, unsigned short* __restrict__ h) {
    extern __shared__ unsigned short lds[];
    constexpr int TOT = (CAP / 256) * (HID / 256) * NEXP;   // 1024
    constexpr int TPE = (CAP / 256) * (HID / 256);          // 128
    constexpr int TN  = HID / 256;                          // 16
    const int bid = (blockIdx.x & 7) * (TOT >> 3) + (blockIdx.x >> 3);  // XCD swizzle
    const int e = bid / TPE, tt = bid % TPE, tm = tt / TN, tn = tt % TN;

    const unsigned short* A = disp + ((size_t)e * CAP + tm * 256) * DIM;
    const unsigned short* B = w1t  + ((size_t)e * HID + tn * 256) * DIM;
    f32x4 acc[8][4];
    #pragma unroll
    for (int m = 0; m < 8; ++m)
        #pragma unroll
        for (int n = 0; n < 4; ++n) acc[m][n] = (f32x4){0.f, 0.f, 0.f, 0.f};

    mainloop256<DIM>(A, B, lds, acc);

    const int l = threadIdx.x & 63, w = threadIdx.x >> 6;
    const int l16 = l & 15, kh4 = l >> 4;
    const int wm = w >> 2, wn = w & 3;
    const float* b1e = b1 + (size_t)e * HID + tn * 256;
    float bias[4];
    #pragma unroll
    for (int n = 0; n < 4; ++n) bias[n] = b1e[wn * 64 + n * 16 + l16];
    unsigned short* H = h + ((size_t)e * CAP + tm * 256) * HID + tn * 256;
    #pragma unroll
    for (int m = 0; m < 8; ++m)
        #pragma unroll
        for (int n = 0; n < 4; ++n)
            #pragma unroll
            for (int r = 0; r < 4; ++r) {
                int row = wm * 128 + m * 16 + kh4 * 4 + r;   // C/D: row=(lane>>4)*4+reg
                int col = wn * 64 + n * 16 + l16;            //      col=lane&15
                H[(size_t)row * HID + col] = f2bf(gelu_f(acc[m][n][r] + bias[n]));
            }
}

// GEMM2: y[e] = h[e] @ w2[e] + b2[e] -> plain f32 stores (no atomics)
__global__ __launch_bounds__(512, 2) void gemm2_kernel(
        const unsigned short* __restrict__ h, const unsigned short* __restrict__ w2t,
        const float* __restrict__ b2, float* __restrict__ y) {
    extern __shared__ unsigned short lds[];
    constexpr int TOT = (CAP / 256) * (DIM / 256) * NEXP;   // 256
    constexpr int TPE = (CAP / 256) * (DIM / 256);          // 32
    constexpr int TN  = DIM / 256;                          // 4
    const int bid = (blockIdx.x & 7) * (TOT >> 3) + (blockIdx.x >> 3);  // XCD swizzle
    const int e = bid / TPE, tt = bid % TPE, tm = tt / TN, tn = tt % TN;

    const unsigned short* A = h   + ((size_t)e * CAP + tm * 256) * HID;
    const unsigned short* B = w2t + ((size_t)e * DIM + tn * 256) * HID;
    f32x4 acc[8][4];
    #pragma unroll
    for (int m = 0; m < 8; ++m)
        #pragma unroll
        for (int n = 0; n < 4; ++n) acc[m][n] = (f32x4){0.f, 0.f, 0.f, 0.f};

    mainloop256<HID>(A, B, lds, acc);

    const int l = threadIdx.x & 63, w = threadIdx.x >> 6;
    const int l16 = l & 15, kh4 = l >> 4;
    const int wm = w >> 2, wn = w & 3;
    const float* b2e = b2 + (size_t)e * DIM + tn * 256;
    float bias[4];
    #pragma unroll
    for (int n = 0; n < 4; ++n) bias[n] = b2e[wn * 64 + n * 16 + l16];
    float* Y = y + ((size_t)e * CAP + tm * 256) * DIM + tn * 256;
    #pragma unroll
    for (int m = 0; m < 8; ++m)
        #pragma unroll
        for (int n = 0; n < 4; ++n)
            #pragma unroll
            for (int r = 0; r < 4; ++r) {
                int row = wm * 128 + m * 16 + kh4 * 4 + r;
                int col = wn * 64 + n * 16 + l16;
                Y[(size_t)row * DIM + col] = acc[m][n][r] + bias[n];
            }
}

// ---------------------------------------------------------------------------
// combine: out[n] = g0*y[slot0] + g1*y[slot1]
// ---------------------------------------------------------------------------
__global__ __launch_bounds__(256) void combine_kernel(
        const float* __restrict__ y, const int* __restrict__ tok_slot,
        const float* __restrict__ tok_g, float* __restrict__ out) {
    int n = blockIdx.x, t = threadIdx.x;
    int s0 = tok_slot[n * 2], s1 = tok_slot[n * 2 + 1];
    float g0 = tok_g[n * 2], g1 = tok_g[n * 2 + 1];
    f32x4 r = {0.f, 0.f, 0.f, 0.f};
    if (s0 >= 0) {
        f32x4 v = *(const f32x4*)(y + (size_t)s0 * DIM + t * 4);
        r[0] = g0 * v[0]; r[1] = g0 * v[1]; r[2] = g0 * v[2]; r[3] = g0 * v[3];
    }
    if (s1 >= 0) {
        f32x4 v = *(const f32x4*)(y + (size_t)s1 * DIM + t * 4);
        r[0] += g1 * v[0]; r[1] += g1 * v[1]; r[2] += g1 * v[2]; r[3] += g1 * v[3];
    }
    *(f32x4*)(out + (size_t)n * DIM + t * 4) = r;
}

// ---------------------------------------------------------------------------
extern "C" void kernel_launch(void* const* d_in, const int* in_sizes, int n_in,
                              void* d_out, int out_size, void* d_ws, size_t ws_size,
                              hipStream_t stream) {
    (void)in_sizes; (void)n_in; (void)out_size; (void)ws_size;
    const float* x  = (const float*)d_in[0];
    const float* wg = (const float*)d_in[1];
    const float* w1 = (const float*)d_in[2];
    const float* b1 = (const float*)d_in[3];
    const float* w2 = (const float*)d_in[4];
    const float* b2 = (const float*)d_in[5];
    float* out = (float*)d_out;

    char* ws = (char*)d_ws;
    size_t off = 0;
    unsigned short* w1t  = (unsigned short*)(ws + off); off += (size_t)NEXP * HID * DIM * 2;  // 64 MB
    unsigned short* w2t  = (unsigned short*)(ws + off); off += (size_t)NEXP * DIM * HID * 2;  // 64 MB
    unsigned short* disp = (unsigned short*)(ws + off); off += (size_t)NEXP * CAP * DIM * 2;  // 32 MB
    unsigned short* hbuf = (unsigned short*)(ws + off); off += (size_t)NEXP * CAP * HID * 2;  // 128 MB
    int*   slot_token = (int*)  (ws + off); off += (size_t)NEXP * CAP * 4;
    int*   tok_e      = (int*)  (ws + off); off += (size_t)N_TOK * 2 * 4;
    float* tok_g      = (float*)(ws + off); off += (size_t)N_TOK * 2 * 4;
    int*   tok_slot   = (int*)  (ws + off); off += (size_t)N_TOK * 2 * 4;
    float* ybuf = (float*)w1t;   // w1t (64 MB) dead after gemm1; fits f32 y exactly

    hipFuncSetAttribute((const void*)gemm1_kernel,
                        hipFuncAttributeMaxDynamicSharedMemorySize, 131072);
    hipFuncSetAttribute((const void*)gemm2_kernel,
                        hipFuncAttributeMaxDynamicSharedMemorySize, 131072);

    hipLaunchKernelGGL(init_kernel, dim3(NEXP * CAP / 256), dim3(256), 0, stream,
                       slot_token);
    hipLaunchKernelGGL(transpose_convert_kernel, dim3(HID / 64, DIM / 64, NEXP), dim3(256), 0, stream,
                       w1, w1t, DIM, HID);
    hipLaunchKernelGGL(transpose_convert_kernel, dim3(DIM / 64, HID / 64, NEXP), dim3(256), 0, stream,
                       w2, w2t, HID, DIM);
    hipLaunchKernelGGL(gate_kernel, dim3(N_TOK / 4), dim3(256), 0, stream, x, wg, tok_e, tok_g);
    hipLaunchKernelGGL(route_kernel, dim3(1), dim3(512), 0, stream,
                       tok_e, slot_token, tok_slot);
    hipLaunchKernelGGL(dispatch_kernel, dim3(NEXP * CAP), dim3(256), 0, stream,
                       x, slot_token, disp);
    hipLaunchKernelGGL(gemm1_kernel, dim3((CAP / 256) * (HID / 256) * NEXP), dim3(512), 131072, stream,
                       disp, w1t, b1, hbuf);
    hipLaunchKernelGGL(gemm2_kernel, dim3((CAP / 256) * (DIM / 256) * NEXP), dim3(512), 131072, stream,
                       hbuf, w2t, b2, ybuf);
    hipLaunchKernelGGL(combine_kernel, dim3(N_TOK), dim3(256), 0, stream,
                       ybuf, tok_slot, tok_g, out);
}